// Round 5
// baseline (160.662 us; speedup 1.0000x reference)
//
#include <hip/hip_runtime.h>
#include <hip/hip_fp16.h>
#include <math.h>

#define HP   2080          // padded height (2048 + 2*16)
#define WP   2080          // padded width
#define MARG 16
#define HOUT 2048
#define WOUT 2048
#define RAD  16            // truncation radius; tail mass ~2e-7

// 64x64 binning
#define BSH  6
#define BT   33            // ceil(2080/64); rows>=2063 empty (positions live in [16,2062))
#define NB   1089          // 33*33 bins
#define CAP  1536          // records per bin (mean ~979, max ~1120; 13 sigma headroom)

// scatter shape
#define NBLK 256
#define THR  1024
#define PPT  4             // 256*1024*4 = 1,048,576 >= N
#define RCAP 4224          // per-block LDS record slots (exactly 4096 points max, no dups)

#define AST  97            // conv frame stride (96 + 1 pad, odd -> <=2-way banks)

// exact discrete tap via Poisson summation: g[n] = sqrt(pi/200)*exp(-pi^2 n^2/200)
__device__ __forceinline__ void make_weights(float* wreg) {
#pragma unroll
    for (int t = 0; t <= RAD; ++t)
        wreg[t] = 0.12533141373155003f * __expf(-0.04934802200544679f * (float)(t * t));
}

// ---------------------------------------------------------------------------
// pass 1: bin records at 64x64 granularity (ONE record per point -- no halo
// dup; the fused consumer reads the 3x3 neighborhood instead). Per-block:
// LDS count -> pair-scan over 1089 bins -> one global cursor reservation per
// (block,bin) -> records sorted into LDS by bin -> coalesced copy-out.
// ---------------------------------------------------------------------------
__global__ __launch_bounds__(THR) void scatter_kernel(const float2* __restrict__ pos,
                                                      const float* __restrict__ inten,
                                                      int* __restrict__ cursor,   // [NB], zeroed
                                                      ushort4* __restrict__ bins,
                                                      int n) {
    __shared__ int     lhist[NB];
    __shared__ int     lofs[NB];
    __shared__ int     lbase[NB];
    __shared__ int     wsum[16];
    __shared__ int     stot;
    __shared__ ushort4 lrec[RCAP];
    __shared__ ushort  lbin[RCAP];

    const int tid = threadIdx.x;
    for (int i = tid; i < NB; i += THR) lhist[i] = 0;
    __syncthreads();

    const int stride = NBLK * THR;
    const int start  = blockIdx.x * THR + tid;
    unsigned ra[PPT], rb[PPT], rc[PPT];
#pragma unroll
    for (int it = 0; it < PPT; ++it) {
        int i = start + it * stride;
        if (i < n) {
            float2 p = pos[i];
            float I  = inten[i];
            float px = p.x + MARG, py = p.y + MARG;
            int col = (int)floorf(px), row = (int)floorf(py);
            row = min(max(row, 0), HP - 1);
            col = min(max(col, 0), WP - 1);
            float dy = py - (float)row, dx = px - (float)col;
            ra[it] = ((unsigned)row << 12) | (unsigned)col;
            rb[it] = (unsigned)__half_as_ushort(__float2half(dx))
                   | ((unsigned)__half_as_ushort(__float2half(dy)) << 16);
            rc[it] = (unsigned)__half_as_ushort(__float2half(I));
            atomicAdd(&lhist[(row >> BSH) * BT + (col >> BSH)], 1);
        } else ra[it] = 0xffffffffu;
    }
    __syncthreads();

    // ---- exclusive scan over 1089 bins: 2 bins/thread + wave scan ----
    const int b0 = 2 * tid, b1 = 2 * tid + 1;
    int c0 = (b0 < NB) ? lhist[b0] : 0;
    int c1 = (b1 < NB) ? lhist[b1] : 0;
    int cp = c0 + c1;
    int incl = cp;
    for (int d = 1; d < 64; d <<= 1) {
        int u = __shfl_up(incl, d, 64);
        if ((tid & 63) >= d) incl += u;
    }
    if ((tid & 63) == 63) wsum[tid >> 6] = incl;
    __syncthreads();
    if (tid == 0) {
        int s = 0;
        for (int w = 0; w < 16; ++w) { int x = wsum[w]; wsum[w] = s; s += x; }
        stot = s;
    }
    __syncthreads();
    const int ebase = incl - cp + wsum[tid >> 6];
    if (b0 < NB) {
        lofs[b0]  = ebase;
        lbase[b0] = (c0 > 0) ? atomicAdd(&cursor[b0], c0) : 0;
        lhist[b0] = 0;
    }
    if (b1 < NB) {
        lofs[b1]  = ebase + c0;
        lbase[b1] = (c1 > 0) ? atomicAdd(&cursor[b1], c1) : 0;
        lhist[b1] = 0;
    }
    __syncthreads();

    // ---- sort records into LDS by bin ----
#pragma unroll
    for (int it = 0; it < PPT; ++it) {
        if (ra[it] != 0xffffffffu) {
            int row = (int)(ra[it] >> 12), col = (int)(ra[it] & 4095u);
            int bin = (row >> BSH) * BT + (col >> BSH);
            int rank = atomicAdd(&lhist[bin], 1);
            int slot = lofs[bin] + rank;
            if (slot < RCAP) {
                ushort4 rec;
                rec.x = (unsigned short)(((row & 63) << 6) | (col & 63));
                rec.y = (unsigned short)(rb[it] & 0xffffu);
                rec.z = (unsigned short)(rb[it] >> 16);
                rec.w = (unsigned short)rc[it];
                lrec[slot] = rec;
                lbin[slot] = (unsigned short)bin;
            }
        }
    }
    __syncthreads();

    // ---- coalesced copy-out: consecutive lanes -> consecutive slots ----
    const int total = min(stot, RCAP);
    for (int j = tid; j < total; j += THR) {
        int b = lbin[j];
        int g = lbase[b] + (j - lofs[b]);
        if (g < CAP) bins[(size_t)b * CAP + g] = lrec[j];
    }
}

// ---------------------------------------------------------------------------
// pass 2 (fused splat + conv): per 64x64 output tile, the separable 33-tap
// conv needs canvas rows/cols [64t .. 64t+95]. Those taps come exclusively
// from records in the 3x3 bin neighborhood (positions never wrap: they live
// in [16,2062)). Read the 9 bins' records load-balanced via a segment prefix,
// splat accepted taps into a 96x96 LDS frame, hconv in place, vconv, store.
// The canvas never exists in HBM.
// ---------------------------------------------------------------------------
__global__ __launch_bounds__(512) void splat_conv(const ushort4* __restrict__ bins,
                                                  const int* __restrict__ cursor,
                                                  float* __restrict__ out) {
    __shared__ float A[96 * AST];   // 37.2 KB frame / hconv result (in place)
    __shared__ int   soff[10];      // segment prefix over the 9 neighbor bins

    const int tid = threadIdx.x;
    // chunked XCD swizzle: each XCD gets 4 contiguous tile-rows -> its 6 bin-rows
    // (198 bins ~ 2.4 MB of records) fit the 4 MB per-XCD L2.
    const int b  = blockIdx.x;                 // 0..1023
    const int wg = (b & 7) * 128 + (b >> 3);
    const int tI = wg >> 5, tJ = wg & 31;      // 32x32 output tiles

    if (tid == 0) {
        int s = 0;
        soff[0] = 0;
        for (int seg = 0; seg < 9; ++seg) {
            int dr = seg / 3 - 1, dc = seg % 3 - 1;
            int bR = tI + dr, bC = tJ + dc;
            int cnt = 0;
            if (bR >= 0 && bR < BT && bC >= 0 && bC < BT)
                cnt = min(cursor[bR * BT + bC], CAP);
            s += cnt;
            soff[seg + 1] = s;
        }
    }
    for (int i = tid; i < 96 * AST; i += 512) A[i] = 0.0f;
    __syncthreads();

    const int o1 = soff[1], o2 = soff[2], o3 = soff[3], o4 = soff[4];
    const int o5 = soff[5], o6 = soff[6], o7 = soff[7], o8 = soff[8];
    const int T  = soff[9];

    for (int j = tid; j < T; j += 512) {
        int s = (j >= o1) + (j >= o2) + (j >= o3) + (j >= o4)
              + (j >= o5) + (j >= o6) + (j >= o7) + (j >= o8);
        int dr = ((s >= 3) ? 1 : 0) + ((s >= 6) ? 1 : 0) - 1;
        int dc = s - (dr + 1) * 3 - 1;
        int local = j - soff[s];                         // LDS read (<=9 addrs/wave)
        int bin = (tI + dr) * BT + (tJ + dc);
        ushort4 r = bins[(size_t)bin * CAP + local];
        int lr = (r.x >> 6) & 63, lc = r.x & 63;
        int fr = (dr << 6) + lr;                         // frame row of tap 0
        int fc = (dc << 6) + lc;
        if ((unsigned)(fr + 1) <= 96u && (unsigned)(fc + 1) <= 96u) {
            float dx = __half2float(__ushort_as_half(r.y));
            float dy = __half2float(__ushort_as_half(r.z));
            float I  = __half2float(__ushort_as_half(r.w));
            float wy1 = dy * I, wy0 = I - wy1;
            float omdx = 1.0f - dx;
            bool r0 = (fr >= 0), r1 = (fr <= 94);
            bool c0 = (fc >= 0), c1 = (fc <= 94);
            float* base = &A[fr * AST + fc];
            if (r0 && c0) atomicAdd(base,           wy0 * omdx);
            if (r0 && c1) atomicAdd(base + 1,       wy0 * dx);
            if (r1 && c0) atomicAdd(base + AST,     wy1 * omdx);
            if (r1 && c1) atomicAdd(base + AST + 1, wy1 * dx);
        }
    }
    __syncthreads();

    float wreg[RAD + 1];
    make_weights(wreg);

    // ---- hconv in place: all 8 octets of a row sit in one wave (8 tid/row,
    // wave=64) -> lockstep load-then-store is race-free ----
    for (int half = 0; half < 2; ++half) {
        const int j = (tid >> 3) + (half << 6);
        if (j < 96) {
            const int o = (tid & 7) << 3;
            float* Ar = &A[j * AST + o];
            float Wf[40];
#pragma unroll
            for (int t = 0; t < 40; ++t) Wf[t] = Ar[t];
            float a[8] = {0, 0, 0, 0, 0, 0, 0, 0};
#pragma unroll
            for (int t = 0; t < 40; ++t) {
                float v = Wf[t];
#pragma unroll
                for (int k = 0; k < 8; ++k)
                    if (t >= k && t <= k + 32)
                        a[k] += v * wreg[(t - k - 16 < 0) ? (k + 16 - t) : (t - k - 16)];
            }
#pragma unroll
            for (int k = 0; k < 8; ++k) Ar[k] = a[k];
        }
    }
    __syncthreads();

    // ---- vconv + store: thread covers 8 rows x 1 col ----
    const int lx = tid & 63;
    const int y0 = (tid >> 6) << 3;
    float Wf[40];
#pragma unroll
    for (int t = 0; t < 40; ++t) Wf[t] = A[(y0 + t) * AST + lx];
    float a[8] = {0, 0, 0, 0, 0, 0, 0, 0};
#pragma unroll
    for (int t = 0; t < 40; ++t) {
        float v = Wf[t];
#pragma unroll
        for (int k = 0; k < 8; ++k)
            if (t >= k && t <= k + 32)
                a[k] += v * wreg[(t - k - 16 < 0) ? (k + 16 - t) : (t - k - 16)];
    }
    const int orow = (tI << 6) + y0, ocol = (tJ << 6) + lx;
#pragma unroll
    for (int k = 0; k < 8; ++k)
        out[(size_t)(orow + k) * WOUT + ocol] = a[k];
}

extern "C" void kernel_launch(void* const* d_in, const int* in_sizes, int n_in,
                              void* d_out, int out_size, void* d_ws, size_t ws_size,
                              hipStream_t stream) {
    const float2* pos   = (const float2*)d_in[0];   // (N,2) as (x,y)
    const float*  inten = (const float*)d_in[1];
    int n = in_sizes[1];

    ushort4* bins   = (ushort4*)d_ws;                                   // 1089*1536*8 = 13.4 MB
    int*     cursor = (int*)((char*)d_ws + (size_t)NB * CAP * sizeof(ushort4));

    hipMemsetAsync(cursor, 0, NB * sizeof(int), stream);
    scatter_kernel<<<NBLK, THR, 0, stream>>>(pos, inten, cursor, bins, n);
    splat_conv<<<1024, 512, 0, stream>>>(bins, cursor, (float*)d_out);
}

// Round 6
// 152.295 us; speedup vs baseline: 1.0549x; 1.0549x over previous
//
#include <hip/hip_runtime.h>
#include <hip/hip_fp16.h>
#include <math.h>

#define HP   2080          // padded height (2048 + 2*16)
#define WP   2080          // padded width
#define MARG 16
#define HOUT 2048
#define WOUT 2048
#define RAD  16            // truncation radius; tail mass ~2e-7

#define TGRID 32           // 32x32 output tiles of 64x64
#define NBIN  1024         // one bin per output tile
#define CAP   2560         // records per tile (mean ~2248, +6.6 sigma)

// scatter shape
#define NBLK 512
#define THR  1024
#define PPT  2             // 512*1024*2 = 1,048,576 >= N
#define RCAP 5120          // per-block record slots (mean 4705, +8 sigma)

#define AST  97            // conv frame stride (96 + 1 pad, odd -> <=2-way banks)
#define INV  0xffffffffu

// exact discrete tap via Poisson summation: g[n] = sqrt(pi/200)*exp(-pi^2 n^2/200)
__device__ __forceinline__ void make_weights(float* wreg) {
#pragma unroll
    for (int t = 0; t <= RAD; ++t)
        wreg[t] = 0.12533141373155003f * __expf(-0.04934802200544679f * (float)(t * t));
}

// ---------------------------------------------------------------------------
// pass 1: duplicate each point into every output tile whose 96x96 conv frame
// it touches (frame row fr = row - 64*tI must lie in [-1,95]; 1-2 tiles per
// dim, mean 2.30 records/point). Records carry frame-local coords so the
// consumer does zero rejection work. The histogram atomicAdd's RETURN VALUE
// is kept in registers as the record's final rank -- no second atomic pass.
// Records are sorted into LDS by bin, then copied out flat (consecutive
// lanes -> consecutive slots -> coalesced runs).
// ---------------------------------------------------------------------------
__global__ __launch_bounds__(THR) void scatter_kernel(const float2* __restrict__ pos,
                                                      const float* __restrict__ inten,
                                                      int* __restrict__ cursor,   // [NBIN], zeroed
                                                      ushort4* __restrict__ bins,
                                                      int n) {
    __shared__ int     lhist[NBIN];
    __shared__ int     lofs[NBIN];
    __shared__ int     lbase[NBIN];
    __shared__ int     wsum[16];
    __shared__ int     stot;
    __shared__ ushort4 lrec[RCAP];   // 40 KB
    __shared__ ushort  lbin[RCAP];   // 10 KB

    const int tid = threadIdx.x;
    lhist[tid] = 0;                  // THR == NBIN
    __syncthreads();

    const int stride = NBLK * THR;
    const int start  = blockIdx.x * THR + tid;
    unsigned ra[PPT], rb[PPT], rc[PPT];
    unsigned p0[PPT], p1[PPT], p2[PPT], p3[PPT];   // (bin<<16)|rank, statically indexed

#pragma unroll
    for (int it = 0; it < PPT; ++it) {
        int i = start + it * stride;
        p0[it] = p1[it] = p2[it] = p3[it] = INV;
        if (i < n) {
            float2 p = pos[i];
            float I  = inten[i];
            float px = p.x + MARG, py = p.y + MARG;
            int col = (int)floorf(px), row = (int)floorf(py);
            row = min(max(row, 0), HP - 1);
            col = min(max(col, 0), WP - 1);
            float dy = py - (float)row, dx = px - (float)col;
            ra[it] = ((unsigned)row << 12) | (unsigned)col;
            rb[it] = (unsigned)__half_as_ushort(__float2half(dx))
                   | ((unsigned)__half_as_ushort(__float2half(dy)) << 16);
            rc[it] = (unsigned)__half_as_ushort(__float2half(I));
            // tiles with fr = row-64*tI in [-1,95]: tI in [ceil((row-95)/64), floor((row+1)/64)]
            int tIlo = max(0, ((row + 32) >> 6) - 1), tIhi = min(TGRID - 1, (row + 1) >> 6);
            int tJlo = max(0, ((col + 32) >> 6) - 1), tJhi = min(TGRID - 1, (col + 1) >> 6);
            int b00 = (tIlo << 5) | tJlo;
            p0[it] = ((unsigned)b00 << 16) | (unsigned)atomicAdd(&lhist[b00], 1);
            if (tJhi > tJlo) {
                int b = (tIlo << 5) | tJhi;
                p1[it] = ((unsigned)b << 16) | (unsigned)atomicAdd(&lhist[b], 1);
            }
            if (tIhi > tIlo) {
                int b = (tIhi << 5) | tJlo;
                p2[it] = ((unsigned)b << 16) | (unsigned)atomicAdd(&lhist[b], 1);
                if (tJhi > tJlo) {
                    int b2 = (tIhi << 5) | tJhi;
                    p3[it] = ((unsigned)b2 << 16) | (unsigned)atomicAdd(&lhist[b2], 1);
                }
            }
        }
    }
    __syncthreads();

    // ---- exclusive scan, exactly 1 bin per thread ----
    int c = lhist[tid];
    int incl = c;
    for (int d = 1; d < 64; d <<= 1) {
        int u = __shfl_up(incl, d, 64);
        if ((tid & 63) >= d) incl += u;
    }
    if ((tid & 63) == 63) wsum[tid >> 6] = incl;
    __syncthreads();
    if (tid == 0) {
        int s = 0;
        for (int w = 0; w < 16; ++w) { int x = wsum[w]; wsum[w] = s; s += x; }
        stot = s;
    }
    __syncthreads();
    lofs[tid]  = incl - c + wsum[tid >> 6];
    lbase[tid] = (c > 0) ? atomicAdd(&cursor[tid], c) : 0;
    __syncthreads();

    // ---- place records into LDS by bin using the saved ranks (no atomics) ----
#pragma unroll
    for (int it = 0; it < PPT; ++it) {
        const int row = (int)(ra[it] >> 12), col = (int)(ra[it] & 4095u);
        ushort4 rec;
        rec.y = (unsigned short)(rb[it] & 0xffffu);
        rec.z = (unsigned short)(rb[it] >> 16);
        rec.w = (unsigned short)rc[it];
        auto place = [&](unsigned pv) {
            if (pv != INV) {
                int bin  = (int)(pv >> 16);
                int rank = (int)(pv & 0xffffu);
                int fr1  = row - ((bin >> 5) << 6) + 1;   // 0..96
                int fc1  = col - ((bin & 31) << 6) + 1;   // 0..96
                int slot = lofs[bin] + rank;
                if (slot < RCAP) {
                    rec.x = (unsigned short)((fr1 << 7) | fc1);
                    lrec[slot] = rec;
                    lbin[slot] = (unsigned short)bin;
                }
            }
        };
        place(p0[it]); place(p1[it]); place(p2[it]); place(p3[it]);
    }
    __syncthreads();

    // ---- coalesced copy-out: consecutive lanes -> consecutive slots ----
    const int total = min(stot, RCAP);
    for (int j = tid; j < total; j += THR) {
        int b = lbin[j];
        int g = lbase[b] + (j - lofs[b]);
        if (g < CAP) bins[(size_t)b * CAP + g] = lrec[j];
    }
}

// ---------------------------------------------------------------------------
// pass 2 (fused splat + conv): per 64x64 output tile, read exactly this
// tile's records (frame-local coords, zero discard), splat into a 96x96 LDS
// frame with guarded LDS atomics, hconv in place, vconv, store. The canvas
// never exists in HBM and every record byte fetched is used.
// ---------------------------------------------------------------------------
__global__ __launch_bounds__(512) void splat_conv(const ushort4* __restrict__ bins,
                                                  const int* __restrict__ cursor,
                                                  float* __restrict__ out) {
    __shared__ float A[96 * AST];   // 37.2 KB frame / hconv result (in place)
    const int tid = threadIdx.x;
    const int b  = blockIdx.x;
    const int tI = b >> 5, tJ = b & 31;

    float4* A4 = (float4*)A;        // 96*97 = 9312 floats = 2328 float4s exactly
    for (int i = tid; i < 2328; i += 512) A4[i] = make_float4(0.f, 0.f, 0.f, 0.f);
    __syncthreads();

    const int cnt = min(cursor[b], CAP);
    const ushort4* bp = bins + (size_t)b * CAP;
    for (int j = tid; j < cnt; j += 512) {
        ushort4 r = bp[j];
        int fr1 = r.x >> 7, fc1 = r.x & 127;              // 0..96
        float dx = __half2float(__ushort_as_half(r.y));
        float dy = __half2float(__ushort_as_half(r.z));
        float I  = __half2float(__ushort_as_half(r.w));
        float wy1 = dy * I, wy0 = I - wy1;
        float wx1 = dx, wx0 = 1.0f - dx;
        int base = (fr1 - 1) * AST + (fc1 - 1);
        bool r0 = (fr1 >= 1), r1 = (fr1 <= 95);
        bool c0 = (fc1 >= 1), c1 = (fc1 <= 95);
        if (r0 && c0) atomicAdd(&A[base],           wy0 * wx0);
        if (r0 && c1) atomicAdd(&A[base + 1],       wy0 * wx1);
        if (r1 && c0) atomicAdd(&A[base + AST],     wy1 * wx0);
        if (r1 && c1) atomicAdd(&A[base + AST + 1], wy1 * wx1);
    }
    __syncthreads();

    float wreg[RAD + 1];
    make_weights(wreg);

    // ---- hconv in place: each row's 8 octets live in one wave (lockstep) ----
    for (int half = 0; half < 2; ++half) {
        const int j = (tid >> 3) + (half << 6);
        if (j < 96) {
            const int o = (tid & 7) << 3;
            float* Ar = &A[j * AST + o];
            float Wf[40];
#pragma unroll
            for (int t = 0; t < 40; ++t) Wf[t] = Ar[t];
            float a[8] = {0, 0, 0, 0, 0, 0, 0, 0};
#pragma unroll
            for (int t = 0; t < 40; ++t) {
                float v = Wf[t];
#pragma unroll
                for (int k = 0; k < 8; ++k)
                    if (t >= k && t <= k + 32)
                        a[k] += v * wreg[(t - k - 16 < 0) ? (k + 16 - t) : (t - k - 16)];
            }
#pragma unroll
            for (int k = 0; k < 8; ++k) Ar[k] = a[k];
        }
    }
    __syncthreads();

    // ---- vconv + store: thread covers 8 rows x 1 col ----
    const int lx = tid & 63;
    const int y0 = (tid >> 6) << 3;
    float Wf[40];
#pragma unroll
    for (int t = 0; t < 40; ++t) Wf[t] = A[(y0 + t) * AST + lx];
    float a[8] = {0, 0, 0, 0, 0, 0, 0, 0};
#pragma unroll
    for (int t = 0; t < 40; ++t) {
        float v = Wf[t];
#pragma unroll
        for (int k = 0; k < 8; ++k)
            if (t >= k && t <= k + 32)
                a[k] += v * wreg[(t - k - 16 < 0) ? (k + 16 - t) : (t - k - 16)];
    }
    const int orow = (tI << 6) + y0, ocol = (tJ << 6) + lx;
#pragma unroll
    for (int k = 0; k < 8; ++k)
        out[(size_t)(orow + k) * WOUT + ocol] = a[k];
}

extern "C" void kernel_launch(void* const* d_in, const int* in_sizes, int n_in,
                              void* d_out, int out_size, void* d_ws, size_t ws_size,
                              hipStream_t stream) {
    const float2* pos   = (const float2*)d_in[0];   // (N,2) as (x,y)
    const float*  inten = (const float*)d_in[1];
    int n = in_sizes[1];

    ushort4* bins   = (ushort4*)d_ws;                                   // 1024*2560*8 = 21.0 MB
    int*     cursor = (int*)((char*)d_ws + (size_t)NBIN * CAP * sizeof(ushort4));

    hipMemsetAsync(cursor, 0, NBIN * sizeof(int), stream);
    scatter_kernel<<<NBLK, THR, 0, stream>>>(pos, inten, cursor, bins, n);
    splat_conv<<<NBIN, 512, 0, stream>>>(bins, cursor, (float*)d_out);
}

// Round 7
// 140.863 us; speedup vs baseline: 1.1406x; 1.0812x over previous
//
#include <hip/hip_runtime.h>
#include <hip/hip_fp16.h>
#include <math.h>

#define HP   2080          // padded height (2048 + 2*16)
#define WP   2080          // padded width
#define MARG 16
#define HOUT 2048
#define WOUT 2048
#define RAD  16            // truncation radius; tail mass ~2e-7

// 128x64 output tiles (rows x cols): frame 160x96, always in-bounds
#define TROWS 16
#define TCOLS 32
#define NBIN  512          // one bin per output tile
#define CAP   4096         // records per tile (mean ~3724, +6 sigma)

// scatter shape
#define NBLK 256
#define THR  1024
#define PPT  4             // 256*1024*4 = 1,048,576 >= N
#define RCAP 8192          // per-block record slots (mean ~7811, +6 sigma)

#define FH   160           // frame rows
#define AST  97            // frame stride (96 + 1 pad, odd -> <=2-way banks)
#define INV  0xffffffffu

// exact discrete tap via Poisson summation: g[n] = sqrt(pi/200)*exp(-pi^2 n^2/200)
__device__ __forceinline__ void make_weights(float* wreg) {
#pragma unroll
    for (int t = 0; t <= RAD; ++t)
        wreg[t] = 0.12533141373155003f * __expf(-0.04934802200544679f * (float)(t * t));
}

// ---------------------------------------------------------------------------
// pass 1: duplicate each point into every 128x64 tile whose 160x96 conv frame
// it touches (frame row fr1 = row-128*tI+1 in [0,160]; mean 1.91 records/pt).
// Histogram atomicAdd return value IS the record's rank (kept in registers,
// statically indexed) -> no second atomic pass. Records sorted into LDS by
// bin, copied out flat: per-(block,bin) runs ~15 records = 120B ~ 2 full
// cache lines -> near-coalesced global writes.
// ---------------------------------------------------------------------------
__global__ __launch_bounds__(THR) void scatter_kernel(const float2* __restrict__ pos,
                                                      const float* __restrict__ inten,
                                                      int* __restrict__ cursor,   // [NBIN], zeroed
                                                      ushort4* __restrict__ bins,
                                                      int n) {
    __shared__ int     lhist[NBIN];
    __shared__ int     lofs[NBIN];
    __shared__ int     lbase[NBIN];
    __shared__ int     wsum[8];
    __shared__ int     stot;
    __shared__ ushort4 lrec[RCAP];   // 64 KB
    __shared__ ushort  lbin[RCAP];   // 16 KB

    const int tid = threadIdx.x;
    if (tid < NBIN) lhist[tid] = 0;
    __syncthreads();

    const int stride = NBLK * THR;
    const int start  = blockIdx.x * THR + tid;
    unsigned ra[PPT], rb[PPT], rc[PPT];
    unsigned p0[PPT], p1[PPT], p2[PPT], p3[PPT];   // (bin<<16)|rank

#pragma unroll
    for (int it = 0; it < PPT; ++it) {
        int i = start + it * stride;
        p0[it] = p1[it] = p2[it] = p3[it] = INV;
        ra[it] = 0;
        if (i < n) {
            float2 p = pos[i];
            float I  = inten[i];
            float px = p.x + MARG, py = p.y + MARG;
            int col = (int)floorf(px), row = (int)floorf(py);
            row = min(max(row, 0), HP - 1);
            col = min(max(col, 0), WP - 1);
            float dy = py - (float)row, dx = px - (float)col;
            ra[it] = ((unsigned)row << 12) | (unsigned)col;
            rb[it] = (unsigned)__half_as_ushort(__float2half(dx))
                   | ((unsigned)__half_as_ushort(__float2half(dy)) << 16);
            rc[it] = (unsigned)__half_as_ushort(__float2half(I));
            // row-tiles: fr1 = row-128*tI+1 in [0,160]  -> tI in [(row-32)>>7, (row+1)>>7]
            int tIlo = max(0, (row - 32) >> 7), tIhi = min(TROWS - 1, (row + 1) >> 7);
            // col-tiles: fc1 = col-64*tJ+1 in [0,96]    -> tJ in [(col-32)>>6, (col+1)>>6]
            int tJlo = max(0, (col - 32) >> 6), tJhi = min(TCOLS - 1, (col + 1) >> 6);
            int b00 = (tIlo << 5) | tJlo;
            p0[it] = ((unsigned)b00 << 16) | (unsigned)atomicAdd(&lhist[b00], 1);
            if (tJhi > tJlo) {
                int b = (tIlo << 5) | tJhi;
                p1[it] = ((unsigned)b << 16) | (unsigned)atomicAdd(&lhist[b], 1);
            }
            if (tIhi > tIlo) {
                int b = (tIhi << 5) | tJlo;
                p2[it] = ((unsigned)b << 16) | (unsigned)atomicAdd(&lhist[b], 1);
                if (tJhi > tJlo) {
                    int b2 = (tIhi << 5) | tJhi;
                    p3[it] = ((unsigned)b2 << 16) | (unsigned)atomicAdd(&lhist[b2], 1);
                }
            }
        }
    }
    __syncthreads();

    // ---- exclusive scan over 512 bins (waves 0-7) + global reservation ----
    int c = (tid < NBIN) ? lhist[tid] : 0;
    int incl = c;
    for (int d = 1; d < 64; d <<= 1) {
        int u = __shfl_up(incl, d, 64);
        if ((tid & 63) >= d) incl += u;
    }
    if (tid < NBIN && (tid & 63) == 63) wsum[tid >> 6] = incl;
    __syncthreads();
    if (tid == 0) {
        int s = 0;
        for (int w = 0; w < 8; ++w) { int x = wsum[w]; wsum[w] = s; s += x; }
        stot = s;
    }
    __syncthreads();
    if (tid < NBIN) {
        lofs[tid]  = incl - c + wsum[tid >> 6];
        lbase[tid] = (c > 0) ? atomicAdd(&cursor[tid], c) : 0;
    }
    __syncthreads();

    // ---- place records into LDS by bin using the saved ranks (no atomics) ----
#pragma unroll
    for (int it = 0; it < PPT; ++it) {
        const int row = (int)(ra[it] >> 12), col = (int)(ra[it] & 4095u);
        ushort4 rec;
        rec.y = (unsigned short)(rb[it] & 0xffffu);
        rec.z = (unsigned short)(rb[it] >> 16);
        rec.w = (unsigned short)rc[it];
        auto place = [&](unsigned pv) {
            if (pv != INV) {
                int bin  = (int)(pv >> 16);
                int rank = (int)(pv & 0xffffu);
                int fr1  = row - ((bin >> 5) << 7) + 1;   // 0..160 (8 bits)
                int fc1  = col - ((bin & 31) << 6) + 1;   // 0..96  (7 bits)
                int slot = lofs[bin] + rank;
                if (slot < RCAP) {
                    rec.x = (unsigned short)((fr1 << 7) | fc1);
                    lrec[slot] = rec;
                    lbin[slot] = (unsigned short)bin;
                }
            }
        };
        place(p0[it]); place(p1[it]); place(p2[it]); place(p3[it]);
    }
    __syncthreads();

    // ---- coalesced copy-out: consecutive lanes -> consecutive slots ----
    const int total = min(stot, RCAP);
    for (int j = tid; j < total; j += THR) {
        int b = lbin[j];
        int g = lbase[b] + (j - lofs[b]);
        if (g < CAP) bins[(size_t)b * CAP + g] = lrec[j];
    }
}

// ---------------------------------------------------------------------------
// pass 2 (fused splat + conv): per 128x64 output tile, read exactly this
// tile's records (frame-local coords, zero discard), splat into a 160x96 LDS
// frame, hconv in place (row-per-wave lockstep), vconv, store. The canvas
// never exists in HBM. 1024 thr, 60.6 KB LDS -> 2 blocks/CU = 32 waves.
// ---------------------------------------------------------------------------
__global__ __launch_bounds__(1024) void splat_conv(const ushort4* __restrict__ bins,
                                                   const int* __restrict__ cursor,
                                                   float* __restrict__ out) {
    __shared__ float A[FH * AST];   // 60.6 KB frame / hconv result (in place)
    const int tid = threadIdx.x;
    const int b  = blockIdx.x;
    const int tI = b >> 5, tJ = b & 31;

    float4* A4 = (float4*)A;        // 160*97 = 15520 floats = 3880 float4s exactly
    for (int i = tid; i < 3880; i += 1024) A4[i] = make_float4(0.f, 0.f, 0.f, 0.f);
    __syncthreads();

    const int cnt = min(cursor[b], CAP);
    const ushort4* bp = bins + (size_t)b * CAP;
    for (int j = tid; j < cnt; j += 1024) {
        ushort4 r = bp[j];
        int fr1 = r.x >> 7, fc1 = r.x & 127;              // 0..160, 0..96
        float dx = __half2float(__ushort_as_half(r.y));
        float dy = __half2float(__ushort_as_half(r.z));
        float I  = __half2float(__ushort_as_half(r.w));
        float wy1 = dy * I, wy0 = I - wy1;
        float wx1 = dx, wx0 = 1.0f - dx;
        int base = (fr1 - 1) * AST + (fc1 - 1);
        bool r0 = (fr1 >= 1), r1 = (fr1 <= FH - 1);
        bool c0 = (fc1 >= 1), c1 = (fc1 <= 95);
        if (r0 && c0) atomicAdd(&A[base],           wy0 * wx0);
        if (r0 && c1) atomicAdd(&A[base + 1],       wy0 * wx1);
        if (r1 && c0) atomicAdd(&A[base + AST],     wy1 * wx0);
        if (r1 && c1) atomicAdd(&A[base + AST + 1], wy1 * wx1);
    }
    __syncthreads();

    float wreg[RAD + 1];
    make_weights(wreg);

    // ---- hconv in place: 160 rows x 8 octets = 1280 units; each row's 8
    // octets live in one wave (u>>3 = row) -> lockstep read-then-write is
    // race-free; rows are wave-exclusive ----
    for (int u = tid; u < FH * 8; u += 1024) {
        const int j = u >> 3;
        const int o = (u & 7) << 3;
        float* Ar = &A[j * AST + o];
        float Wf[40];
#pragma unroll
        for (int t = 0; t < 40; ++t) Wf[t] = Ar[t];
        float a[8] = {0, 0, 0, 0, 0, 0, 0, 0};
#pragma unroll
        for (int t = 0; t < 40; ++t) {
            float v = Wf[t];
#pragma unroll
            for (int k = 0; k < 8; ++k)
                if (t >= k && t <= k + 32)
                    a[k] += v * wreg[(t - k - 16 < 0) ? (k + 16 - t) : (t - k - 16)];
        }
#pragma unroll
        for (int k = 0; k < 8; ++k) Ar[k] = a[k];
    }
    __syncthreads();

    // ---- vconv + store: thread covers 8 rows x 1 col; 16 row-groups x 64 cols ----
    const int lx = tid & 63;
    const int y0 = (tid >> 6) << 3;      // 0,8,...,120
    float Wf[40];
#pragma unroll
    for (int t = 0; t < 40; ++t) Wf[t] = A[(y0 + t) * AST + lx];
    float a[8] = {0, 0, 0, 0, 0, 0, 0, 0};
#pragma unroll
    for (int t = 0; t < 40; ++t) {
        float v = Wf[t];
#pragma unroll
        for (int k = 0; k < 8; ++k)
            if (t >= k && t <= k + 32)
                a[k] += v * wreg[(t - k - 16 < 0) ? (k + 16 - t) : (t - k - 16)];
    }
    const int orow = (tI << 7) + y0, ocol = (tJ << 6) + lx;
#pragma unroll
    for (int k = 0; k < 8; ++k)
        out[(size_t)(orow + k) * WOUT + ocol] = a[k];
}

extern "C" void kernel_launch(void* const* d_in, const int* in_sizes, int n_in,
                              void* d_out, int out_size, void* d_ws, size_t ws_size,
                              hipStream_t stream) {
    const float2* pos   = (const float2*)d_in[0];   // (N,2) as (x,y)
    const float*  inten = (const float*)d_in[1];
    int n = in_sizes[1];

    ushort4* bins   = (ushort4*)d_ws;                                   // 512*4096*8 = 16.8 MB
    int*     cursor = (int*)((char*)d_ws + (size_t)NBIN * CAP * sizeof(ushort4));

    hipMemsetAsync(cursor, 0, NBIN * sizeof(int), stream);
    scatter_kernel<<<NBLK, THR, 0, stream>>>(pos, inten, cursor, bins, n);
    splat_conv<<<NBIN, 1024, 0, stream>>>(bins, cursor, (float*)d_out);
}

// Round 8
// 114.096 us; speedup vs baseline: 1.4081x; 1.2346x over previous
//
#include <hip/hip_runtime.h>
#include <hip/hip_fp16.h>
#include <math.h>

#define HP   2080          // padded height (2048 + 2*16)
#define WP   2080          // padded width
#define MARG 16
#define HOUT 2048
#define WOUT 2048
#define RAD  16            // truncation radius; tail mass ~2e-7

#define TGRID 32           // 32x32 output tiles of 64x64
#define NBIN  1024         // one bin per output tile
#define CAP   2560         // records per tile (mean ~2248, +6.6 sigma)

// scatter shape (round-6 proven)
#define NBLK 512
#define THR  1024
#define PPT  2             // 512*1024*2 = 1,048,576 >= N
#define RCAP 5120          // per-block record slots (mean 4705, +8 sigma)

#define AST  97            // f32 frame stride (96 + 1 pad)
#define INV  0xffffffffu

#define FSCALE    33554432.0f            // 2^25 fixed-point scale
#define FINVSCALE 2.9802322387695312e-8f // 2^-25

// exact discrete tap via Poisson summation: g[n] = sqrt(pi/200)*exp(-pi^2 n^2/200)
__device__ __forceinline__ void make_weights(float* wreg) {
#pragma unroll
    for (int t = 0; t <= RAD; ++t)
        wreg[t] = 0.12533141373155003f * __expf(-0.04934802200544679f * (float)(t * t));
}

// ---------------------------------------------------------------------------
// pass 1 (round-6 verbatim): duplicate each point into every output tile whose
// 96x96 conv frame it touches; histogram atomicAdd return value IS the rank;
// LDS-sort by bin; coalesced copy-out.
// ---------------------------------------------------------------------------
__global__ __launch_bounds__(THR) void scatter_kernel(const float2* __restrict__ pos,
                                                      const float* __restrict__ inten,
                                                      int* __restrict__ cursor,   // [NBIN], zeroed
                                                      ushort4* __restrict__ bins,
                                                      int n) {
    __shared__ int     lhist[NBIN];
    __shared__ int     lofs[NBIN];
    __shared__ int     lbase[NBIN];
    __shared__ int     wsum[16];
    __shared__ int     stot;
    __shared__ ushort4 lrec[RCAP];   // 40 KB
    __shared__ ushort  lbin[RCAP];   // 10 KB

    const int tid = threadIdx.x;
    lhist[tid] = 0;                  // THR == NBIN
    __syncthreads();

    const int stride = NBLK * THR;
    const int start  = blockIdx.x * THR + tid;
    unsigned ra[PPT], rb[PPT], rc[PPT];
    unsigned p0[PPT], p1[PPT], p2[PPT], p3[PPT];   // (bin<<16)|rank, statically indexed

#pragma unroll
    for (int it = 0; it < PPT; ++it) {
        int i = start + it * stride;
        p0[it] = p1[it] = p2[it] = p3[it] = INV;
        ra[it] = 0;
        if (i < n) {
            float2 p = pos[i];
            float I  = inten[i];
            float px = p.x + MARG, py = p.y + MARG;
            int col = (int)floorf(px), row = (int)floorf(py);
            row = min(max(row, 0), HP - 1);
            col = min(max(col, 0), WP - 1);
            float dy = py - (float)row, dx = px - (float)col;
            ra[it] = ((unsigned)row << 12) | (unsigned)col;
            rb[it] = (unsigned)__half_as_ushort(__float2half(dx))
                   | ((unsigned)__half_as_ushort(__float2half(dy)) << 16);
            rc[it] = (unsigned)__half_as_ushort(__float2half(I));
            int tIlo = max(0, ((row + 32) >> 6) - 1), tIhi = min(TGRID - 1, (row + 1) >> 6);
            int tJlo = max(0, ((col + 32) >> 6) - 1), tJhi = min(TGRID - 1, (col + 1) >> 6);
            int b00 = (tIlo << 5) | tJlo;
            p0[it] = ((unsigned)b00 << 16) | (unsigned)atomicAdd(&lhist[b00], 1);
            if (tJhi > tJlo) {
                int b = (tIlo << 5) | tJhi;
                p1[it] = ((unsigned)b << 16) | (unsigned)atomicAdd(&lhist[b], 1);
            }
            if (tIhi > tIlo) {
                int b = (tIhi << 5) | tJlo;
                p2[it] = ((unsigned)b << 16) | (unsigned)atomicAdd(&lhist[b], 1);
                if (tJhi > tJlo) {
                    int b2 = (tIhi << 5) | tJhi;
                    p3[it] = ((unsigned)b2 << 16) | (unsigned)atomicAdd(&lhist[b2], 1);
                }
            }
        }
    }
    __syncthreads();

    // ---- exclusive scan, exactly 1 bin per thread ----
    int c = lhist[tid];
    int incl = c;
    for (int d = 1; d < 64; d <<= 1) {
        int u = __shfl_up(incl, d, 64);
        if ((tid & 63) >= d) incl += u;
    }
    if ((tid & 63) == 63) wsum[tid >> 6] = incl;
    __syncthreads();
    if (tid == 0) {
        int s = 0;
        for (int w = 0; w < 16; ++w) { int x = wsum[w]; wsum[w] = s; s += x; }
        stot = s;
    }
    __syncthreads();
    lofs[tid]  = incl - c + wsum[tid >> 6];
    lbase[tid] = (c > 0) ? atomicAdd(&cursor[tid], c) : 0;
    __syncthreads();

    // ---- place records into LDS by bin using the saved ranks (no atomics) ----
#pragma unroll
    for (int it = 0; it < PPT; ++it) {
        const int row = (int)(ra[it] >> 12), col = (int)(ra[it] & 4095u);
        ushort4 rec;
        rec.y = (unsigned short)(rb[it] & 0xffffu);
        rec.z = (unsigned short)(rb[it] >> 16);
        rec.w = (unsigned short)rc[it];
        auto place = [&](unsigned pv) {
            if (pv != INV) {
                int bin  = (int)(pv >> 16);
                int rank = (int)(pv & 0xffffu);
                int fr1  = row - ((bin >> 5) << 6) + 1;   // 0..96
                int fc1  = col - ((bin & 31) << 6) + 1;   // 0..96
                int slot = lofs[bin] + rank;
                if (slot < RCAP) {
                    rec.x = (unsigned short)((fr1 << 7) | fc1);
                    lrec[slot] = rec;
                    lbin[slot] = (unsigned short)bin;
                }
            }
        };
        place(p0[it]); place(p1[it]); place(p2[it]); place(p3[it]);
    }
    __syncthreads();

    // ---- coalesced copy-out ----
    const int total = min(stot, RCAP);
    for (int j = tid; j < total; j += THR) {
        int b = lbin[j];
        int g = lbase[b] + (j - lofs[b]);
        if (g < CAP) bins[(size_t)b * CAP + g] = lrec[j];
    }
}

// ---------------------------------------------------------------------------
// pass 2 (fused splat + conv, dual-parity u64 splat): each record's 2x2 tap
// block = 2 rows x 1 column-pair. Frames hold u64 cells = two Q7.25 halves:
//   even pairs p=0..47  cover cols (2p, 2p+1)      at U[r*97 + p]
//   odd  pairs q=0..48  cover cols (2q-1, 2q)      at U[r*97 + 48 + q]
// Any (fc1-1, fc1) lies in exactly one pair of one parity -> exactly 2
// atomicAdd(u64) per record (one per tap row) vs 4 f32 adds. Merge pass
// converts to f32 in the low half of the same LDS region (register-staged,
// single barrier), then hconv in place + vconv + store.
// ---------------------------------------------------------------------------
__device__ __forceinline__ void splat_rec(ushort4 r, unsigned long long* U) {
    int fr1 = r.x >> 7, fc1 = r.x & 127;              // 0..96 each
    float dx = __half2float(__ushort_as_half(r.y));
    float dy = __half2float(__ushort_as_half(r.z));
    float I  = __half2float(__ushort_as_half(r.w));
    float wy1 = dy * I, wy0 = I - wy1;
    float wl, wh; int k;
    if (fc1 & 1) { k = fc1 >> 1;        wl = 1.0f - dx; wh = dx; }                 // even pair
    else {         k = 48 + (fc1 >> 1); wl = (fc1 >= 1) ? 1.0f - dx : 0.0f;        // odd pair
                                        wh = (fc1 <= 95) ? dx : 0.0f; }
    if (fr1 >= 1) {
        unsigned long long v = ((unsigned long long)(unsigned)(wy0 * wh * FSCALE) << 32)
                             |  (unsigned long long)(unsigned)(wy0 * wl * FSCALE);
        atomicAdd(&U[(fr1 - 1) * 97 + k], v);
    }
    if (fr1 <= 95) {
        unsigned long long v = ((unsigned long long)(unsigned)(wy1 * wh * FSCALE) << 32)
                             |  (unsigned long long)(unsigned)(wy1 * wl * FSCALE);
        atomicAdd(&U[fr1 * 97 + k], v);
    }
}

__global__ __launch_bounds__(1024) void splat_conv(const ushort4* __restrict__ bins,
                                                   const int* __restrict__ cursor,
                                                   float* __restrict__ out) {
    __shared__ unsigned long long U[96 * 97];   // 74.5 KB dual-parity frames
    float* A = (float*)U;                        // merged f32 frame [96][AST], low 37.2 KB
    const int tid = threadIdx.x;
    const int b  = blockIdx.x;
    const int tI = b >> 5, tJ = b & 31;

    // prefetch this tile's records (<=3/thread) BEFORE zeroing: HBM latency
    // hides under the LDS zero stores
    const int cnt = min(cursor[b], CAP);
    const ushort4* bp = bins + (size_t)b * CAP;
    const bool h0 = tid < cnt, h1 = tid + 1024 < cnt, h2 = tid + 2048 < cnt;
    ushort4 r0_ = {0,0,0,0}, r1_ = {0,0,0,0}, r2_ = {0,0,0,0};
    if (h0) r0_ = bp[tid];
    if (h1) r1_ = bp[tid + 1024];
    if (h2) r2_ = bp[tid + 2048];

    uint4* U4 = (uint4*)U;                       // 9312 u64 = 4656 uint4
    for (int i = tid; i < 4656; i += 1024) U4[i] = make_uint4(0u, 0u, 0u, 0u);
    __syncthreads();

    if (h0) splat_rec(r0_, U);
    if (h1) splat_rec(r1_, U);
    if (h2) splat_rec(r2_, U);
    __syncthreads();

    // ---- merge u64 parities -> f32 frame (in place, register-staged) ----
    // col 2cp   = lo(even[cp]) + hi(odd[cp])
    // col 2cp+1 = hi(even[cp]) + lo(odd[cp+1])
    float m0a=0,m0b=0,m1a=0,m1b=0,m2a=0,m2b=0,m3a=0,m3b=0,m4a=0,m4b=0;
#define MERGE_READ(K, RA, RB) { int u = tid + (K) * 1024; if (u < 4608) { \
        int r = u / 48, cp = u - r * 48; \
        unsigned long long e  = U[r * 97 + cp]; \
        unsigned long long ol = U[r * 97 + 48 + cp]; \
        unsigned long long orr= U[r * 97 + 48 + cp + 1]; \
        RA = ((float)(unsigned)e         + (float)(unsigned)(ol >> 32)) * FINVSCALE; \
        RB = ((float)(unsigned)(e >> 32) + (float)(unsigned)orr)        * FINVSCALE; } }
    MERGE_READ(0, m0a, m0b)
    MERGE_READ(1, m1a, m1b)
    MERGE_READ(2, m2a, m2b)
    MERGE_READ(3, m3a, m3b)
    MERGE_READ(4, m4a, m4b)
    __syncthreads();
#define MERGE_WRITE(K, RA, RB) { int u = tid + (K) * 1024; if (u < 4608) { \
        int r = u / 48, cp = u - r * 48; \
        A[r * AST + 2 * cp] = RA; A[r * AST + 2 * cp + 1] = RB; } }
    MERGE_WRITE(0, m0a, m0b)
    MERGE_WRITE(1, m1a, m1b)
    MERGE_WRITE(2, m2a, m2b)
    MERGE_WRITE(3, m3a, m3b)
    MERGE_WRITE(4, m4a, m4b)
    __syncthreads();

    float wreg[RAD + 1];
    make_weights(wreg);

    // ---- hconv in place: 96 rows x 8 octets = 768 units; each row's 8
    // octets live in one wave -> lockstep read-then-write is race-free ----
    if (tid < 768) {
        const int j = tid >> 3;
        const int o = (tid & 7) << 3;
        float* Ar = &A[j * AST + o];
        float Wf[40];
#pragma unroll
        for (int t = 0; t < 40; ++t) Wf[t] = Ar[t];
        float a[8] = {0, 0, 0, 0, 0, 0, 0, 0};
#pragma unroll
        for (int t = 0; t < 40; ++t) {
            float v = Wf[t];
#pragma unroll
            for (int k = 0; k < 8; ++k)
                if (t >= k && t <= k + 32)
                    a[k] += v * wreg[(t - k - 16 < 0) ? (k + 16 - t) : (t - k - 16)];
        }
#pragma unroll
        for (int k = 0; k < 8; ++k) Ar[k] = a[k];
    }
    __syncthreads();

    // ---- vconv + store: thread covers 4 rows x 1 col (16 groups x 64 cols) ----
    const int lx = tid & 63;
    const int y0 = (tid >> 6) << 2;      // 0,4,...,60
    float Wf[36];
#pragma unroll
    for (int t = 0; t < 36; ++t) Wf[t] = A[(y0 + t) * AST + lx];
    float a[4] = {0, 0, 0, 0};
#pragma unroll
    for (int t = 0; t < 36; ++t) {
        float v = Wf[t];
#pragma unroll
        for (int k = 0; k < 4; ++k)
            if (t >= k && t <= k + 32)
                a[k] += v * wreg[(t - k - 16 < 0) ? (k + 16 - t) : (t - k - 16)];
    }
    const int orow = (tI << 6) + y0, ocol = (tJ << 6) + lx;
#pragma unroll
    for (int k = 0; k < 4; ++k)
        out[(size_t)(orow + k) * WOUT + ocol] = a[k];
}

extern "C" void kernel_launch(void* const* d_in, const int* in_sizes, int n_in,
                              void* d_out, int out_size, void* d_ws, size_t ws_size,
                              hipStream_t stream) {
    const float2* pos   = (const float2*)d_in[0];   // (N,2) as (x,y)
    const float*  inten = (const float*)d_in[1];
    int n = in_sizes[1];

    ushort4* bins   = (ushort4*)d_ws;                                   // 1024*2560*8 = 21.0 MB
    int*     cursor = (int*)((char*)d_ws + (size_t)NBIN * CAP * sizeof(ushort4));

    hipMemsetAsync(cursor, 0, NBIN * sizeof(int), stream);
    scatter_kernel<<<NBLK, THR, 0, stream>>>(pos, inten, cursor, bins, n);
    splat_conv<<<NBIN, 1024, 0, stream>>>(bins, cursor, (float*)d_out);
}

// Round 9
// 110.253 us; speedup vs baseline: 1.4572x; 1.0349x over previous
//
#include <hip/hip_runtime.h>
#include <hip/hip_fp16.h>
#include <math.h>

#define HP   2080          // padded height (2048 + 2*16)
#define WP   2080          // padded width
#define MARG 16
#define HOUT 2048
#define WOUT 2048
#define RAD  16            // truncation radius; tail mass ~2e-7

#define TGRID 32           // 32x32 output tiles of 64x64
#define NBIN  1024         // one bin per output tile
#define CAP   2560         // records per tile (mean ~2248, +6.6 sigma)

// scatter shape: 256 blocks = 1/CU, ~9.4K records/block -> per-(block,bin)
// runs ~9.2 records = 74B (write-amp ~1.15x vs 1.7x at 512 blocks)
#define NBLK 256
#define THR  1024
#define PPT  4             // 256*1024*4 = 1,048,576 >= N
#define RCAP 10240         // per-block record slots (mean ~9410, +18 sigma)

#define AST  97            // f32 frame stride (96 + 1 pad)
#define INV  0xffffffffu

#define FSCALE    33554432.0f            // 2^25 fixed-point scale
#define FINVSCALE 2.9802322387695312e-8f // 2^-25

// exact discrete tap via Poisson summation: g[n] = sqrt(pi/200)*exp(-pi^2 n^2/200)
__device__ __forceinline__ void make_weights(float* wreg) {
#pragma unroll
    for (int t = 0; t <= RAD; ++t)
        wreg[t] = 0.12533141373155003f * __expf(-0.04934802200544679f * (float)(t * t));
}

// ---------------------------------------------------------------------------
// pass 1: duplicate each point into every output tile whose 96x96 conv frame
// it touches; histogram atomicAdd return value IS the rank (registers,
// statically indexed); LDS-sort by bin; coalesced copy-out in runs of ~9.2
// records (~74B) per (block,bin).
// ---------------------------------------------------------------------------
__global__ __launch_bounds__(THR) void scatter_kernel(const float2* __restrict__ pos,
                                                      const float* __restrict__ inten,
                                                      int* __restrict__ cursor,   // [NBIN], zeroed
                                                      ushort4* __restrict__ bins,
                                                      int n) {
    __shared__ int     lhist[NBIN];
    __shared__ int     lofs[NBIN];
    __shared__ int     lbase[NBIN];
    __shared__ int     wsum[16];
    __shared__ int     stot;
    __shared__ ushort4 lrec[RCAP];   // 80 KB
    __shared__ ushort  lbin[RCAP];   // 20 KB

    const int tid = threadIdx.x;
    lhist[tid] = 0;                  // THR == NBIN
    __syncthreads();

    const int stride = NBLK * THR;
    const int start  = blockIdx.x * THR + tid;
    unsigned ra[PPT], rb[PPT], rc[PPT];
    unsigned p0[PPT], p1[PPT], p2[PPT], p3[PPT];   // (bin<<16)|rank, statically indexed

#pragma unroll
    for (int it = 0; it < PPT; ++it) {
        int i = start + it * stride;
        p0[it] = p1[it] = p2[it] = p3[it] = INV;
        ra[it] = 0;
        if (i < n) {
            float2 p = pos[i];
            float I  = inten[i];
            float px = p.x + MARG, py = p.y + MARG;
            int col = (int)floorf(px), row = (int)floorf(py);
            row = min(max(row, 0), HP - 1);
            col = min(max(col, 0), WP - 1);
            float dy = py - (float)row, dx = px - (float)col;
            ra[it] = ((unsigned)row << 12) | (unsigned)col;
            rb[it] = (unsigned)__half_as_ushort(__float2half(dx))
                   | ((unsigned)__half_as_ushort(__float2half(dy)) << 16);
            rc[it] = (unsigned)__half_as_ushort(__float2half(I));
            int tIlo = max(0, ((row + 32) >> 6) - 1), tIhi = min(TGRID - 1, (row + 1) >> 6);
            int tJlo = max(0, ((col + 32) >> 6) - 1), tJhi = min(TGRID - 1, (col + 1) >> 6);
            int b00 = (tIlo << 5) | tJlo;
            p0[it] = ((unsigned)b00 << 16) | (unsigned)atomicAdd(&lhist[b00], 1);
            if (tJhi > tJlo) {
                int b = (tIlo << 5) | tJhi;
                p1[it] = ((unsigned)b << 16) | (unsigned)atomicAdd(&lhist[b], 1);
            }
            if (tIhi > tIlo) {
                int b = (tIhi << 5) | tJlo;
                p2[it] = ((unsigned)b << 16) | (unsigned)atomicAdd(&lhist[b], 1);
                if (tJhi > tJlo) {
                    int b2 = (tIhi << 5) | tJhi;
                    p3[it] = ((unsigned)b2 << 16) | (unsigned)atomicAdd(&lhist[b2], 1);
                }
            }
        }
    }
    __syncthreads();

    // ---- exclusive scan, exactly 1 bin per thread ----
    int c = lhist[tid];
    int incl = c;
    for (int d = 1; d < 64; d <<= 1) {
        int u = __shfl_up(incl, d, 64);
        if ((tid & 63) >= d) incl += u;
    }
    if ((tid & 63) == 63) wsum[tid >> 6] = incl;
    __syncthreads();
    if (tid == 0) {
        int s = 0;
        for (int w = 0; w < 16; ++w) { int x = wsum[w]; wsum[w] = s; s += x; }
        stot = s;
    }
    __syncthreads();
    lofs[tid]  = incl - c + wsum[tid >> 6];
    lbase[tid] = (c > 0) ? atomicAdd(&cursor[tid], c) : 0;
    __syncthreads();

    // ---- place records into LDS by bin using the saved ranks (no atomics) ----
#pragma unroll
    for (int it = 0; it < PPT; ++it) {
        const int row = (int)(ra[it] >> 12), col = (int)(ra[it] & 4095u);
        ushort4 rec;
        rec.y = (unsigned short)(rb[it] & 0xffffu);
        rec.z = (unsigned short)(rb[it] >> 16);
        rec.w = (unsigned short)rc[it];
        auto place = [&](unsigned pv) {
            if (pv != INV) {
                int bin  = (int)(pv >> 16);
                int rank = (int)(pv & 0xffffu);
                int fr1  = row - ((bin >> 5) << 6) + 1;   // 0..96
                int fc1  = col - ((bin & 31) << 6) + 1;   // 0..96
                int slot = lofs[bin] + rank;
                if (slot < RCAP) {
                    rec.x = (unsigned short)((fr1 << 7) | fc1);
                    lrec[slot] = rec;
                    lbin[slot] = (unsigned short)bin;
                }
            }
        };
        place(p0[it]); place(p1[it]); place(p2[it]); place(p3[it]);
    }
    __syncthreads();

    // ---- coalesced copy-out ----
    const int total = min(stot, RCAP);
    for (int j = tid; j < total; j += THR) {
        int b = lbin[j];
        int g = lbase[b] + (j - lofs[b]);
        if (g < CAP) bins[(size_t)b * CAP + g] = lrec[j];
    }
}

// ---------------------------------------------------------------------------
// pass 2 (round-8 verbatim; fused splat + conv, dual-parity u64 splat):
// each record's 2x2 tap block = 2 rows x 1 column-pair. Frames hold u64
// cells = two Q7.25 halves:
//   even pairs p=0..47  cover cols (2p, 2p+1)      at U[r*97 + p]
//   odd  pairs q=0..48  cover cols (2q-1, 2q)      at U[r*97 + 48 + q]
// Any (fc1-1, fc1) lies in exactly one pair of one parity -> exactly 2
// atomicAdd(u64) per record (one per tap row) vs 4 f32 adds. Merge pass
// converts to f32 in the low half of the same LDS region, then hconv in
// place + vconv + store.
// ---------------------------------------------------------------------------
__device__ __forceinline__ void splat_rec(ushort4 r, unsigned long long* U) {
    int fr1 = r.x >> 7, fc1 = r.x & 127;              // 0..96 each
    float dx = __half2float(__ushort_as_half(r.y));
    float dy = __half2float(__ushort_as_half(r.z));
    float I  = __half2float(__ushort_as_half(r.w));
    float wy1 = dy * I, wy0 = I - wy1;
    float wl, wh; int k;
    if (fc1 & 1) { k = fc1 >> 1;        wl = 1.0f - dx; wh = dx; }                 // even pair
    else {         k = 48 + (fc1 >> 1); wl = (fc1 >= 1) ? 1.0f - dx : 0.0f;        // odd pair
                                        wh = (fc1 <= 95) ? dx : 0.0f; }
    if (fr1 >= 1) {
        unsigned long long v = ((unsigned long long)(unsigned)(wy0 * wh * FSCALE) << 32)
                             |  (unsigned long long)(unsigned)(wy0 * wl * FSCALE);
        atomicAdd(&U[(fr1 - 1) * 97 + k], v);
    }
    if (fr1 <= 95) {
        unsigned long long v = ((unsigned long long)(unsigned)(wy1 * wh * FSCALE) << 32)
                             |  (unsigned long long)(unsigned)(wy1 * wl * FSCALE);
        atomicAdd(&U[fr1 * 97 + k], v);
    }
}

__global__ __launch_bounds__(1024) void splat_conv(const ushort4* __restrict__ bins,
                                                   const int* __restrict__ cursor,
                                                   float* __restrict__ out) {
    __shared__ unsigned long long U[96 * 97];   // 74.5 KB dual-parity frames
    float* A = (float*)U;                        // merged f32 frame [96][AST]
    const int tid = threadIdx.x;
    const int b  = blockIdx.x;
    const int tI = b >> 5, tJ = b & 31;

    // prefetch this tile's records (<=3/thread) BEFORE zeroing
    const int cnt = min(cursor[b], CAP);
    const ushort4* bp = bins + (size_t)b * CAP;
    const bool h0 = tid < cnt, h1 = tid + 1024 < cnt, h2 = tid + 2048 < cnt;
    ushort4 r0_ = {0,0,0,0}, r1_ = {0,0,0,0}, r2_ = {0,0,0,0};
    if (h0) r0_ = bp[tid];
    if (h1) r1_ = bp[tid + 1024];
    if (h2) r2_ = bp[tid + 2048];

    uint4* U4 = (uint4*)U;                       // 9312 u64 = 4656 uint4
    for (int i = tid; i < 4656; i += 1024) U4[i] = make_uint4(0u, 0u, 0u, 0u);
    __syncthreads();

    if (h0) splat_rec(r0_, U);
    if (h1) splat_rec(r1_, U);
    if (h2) splat_rec(r2_, U);
    __syncthreads();

    // ---- merge u64 parities -> f32 frame (in place, register-staged) ----
    float m0a=0,m0b=0,m1a=0,m1b=0,m2a=0,m2b=0,m3a=0,m3b=0,m4a=0,m4b=0;
#define MERGE_READ(K, RA, RB) { int u = tid + (K) * 1024; if (u < 4608) { \
        int r = u / 48, cp = u - r * 48; \
        unsigned long long e  = U[r * 97 + cp]; \
        unsigned long long ol = U[r * 97 + 48 + cp]; \
        unsigned long long orr= U[r * 97 + 48 + cp + 1]; \
        RA = ((float)(unsigned)e         + (float)(unsigned)(ol >> 32)) * FINVSCALE; \
        RB = ((float)(unsigned)(e >> 32) + (float)(unsigned)orr)        * FINVSCALE; } }
    MERGE_READ(0, m0a, m0b)
    MERGE_READ(1, m1a, m1b)
    MERGE_READ(2, m2a, m2b)
    MERGE_READ(3, m3a, m3b)
    MERGE_READ(4, m4a, m4b)
    __syncthreads();
#define MERGE_WRITE(K, RA, RB) { int u = tid + (K) * 1024; if (u < 4608) { \
        int r = u / 48, cp = u - r * 48; \
        A[r * AST + 2 * cp] = RA; A[r * AST + 2 * cp + 1] = RB; } }
    MERGE_WRITE(0, m0a, m0b)
    MERGE_WRITE(1, m1a, m1b)
    MERGE_WRITE(2, m2a, m2b)
    MERGE_WRITE(3, m3a, m3b)
    MERGE_WRITE(4, m4a, m4b)
    __syncthreads();

    float wreg[RAD + 1];
    make_weights(wreg);

    // ---- hconv in place: 96 rows x 8 octets = 768 units; each row's 8
    // octets live in one wave -> lockstep read-then-write is race-free ----
    if (tid < 768) {
        const int j = tid >> 3;
        const int o = (tid & 7) << 3;
        float* Ar = &A[j * AST + o];
        float Wf[40];
#pragma unroll
        for (int t = 0; t < 40; ++t) Wf[t] = Ar[t];
        float a[8] = {0, 0, 0, 0, 0, 0, 0, 0};
#pragma unroll
        for (int t = 0; t < 40; ++t) {
            float v = Wf[t];
#pragma unroll
            for (int k = 0; k < 8; ++k)
                if (t >= k && t <= k + 32)
                    a[k] += v * wreg[(t - k - 16 < 0) ? (k + 16 - t) : (t - k - 16)];
        }
#pragma unroll
        for (int k = 0; k < 8; ++k) Ar[k] = a[k];
    }
    __syncthreads();

    // ---- vconv + store: thread covers 4 rows x 1 col (16 groups x 64 cols) ----
    const int lx = tid & 63;
    const int y0 = (tid >> 6) << 2;      // 0,4,...,60
    float Wf[36];
#pragma unroll
    for (int t = 0; t < 36; ++t) Wf[t] = A[(y0 + t) * AST + lx];
    float a[4] = {0, 0, 0, 0};
#pragma unroll
    for (int t = 0; t < 36; ++t) {
        float v = Wf[t];
#pragma unroll
        for (int k = 0; k < 4; ++k)
            if (t >= k && t <= k + 32)
                a[k] += v * wreg[(t - k - 16 < 0) ? (k + 16 - t) : (t - k - 16)];
    }
    const int orow = (tI << 6) + y0, ocol = (tJ << 6) + lx;
#pragma unroll
    for (int k = 0; k < 4; ++k)
        out[(size_t)(orow + k) * WOUT + ocol] = a[k];
}

extern "C" void kernel_launch(void* const* d_in, const int* in_sizes, int n_in,
                              void* d_out, int out_size, void* d_ws, size_t ws_size,
                              hipStream_t stream) {
    const float2* pos   = (const float2*)d_in[0];   // (N,2) as (x,y)
    const float*  inten = (const float*)d_in[1];
    int n = in_sizes[1];

    ushort4* bins   = (ushort4*)d_ws;                                   // 1024*2560*8 = 21.0 MB
    int*     cursor = (int*)((char*)d_ws + (size_t)NBIN * CAP * sizeof(ushort4));

    hipMemsetAsync(cursor, 0, NBIN * sizeof(int), stream);
    scatter_kernel<<<NBLK, THR, 0, stream>>>(pos, inten, cursor, bins, n);
    splat_conv<<<NBIN, 1024, 0, stream>>>(bins, cursor, (float*)d_out);
}